// Round 7
// baseline (328.717 us; speedup 1.0000x reference)
//
#include <hip/hip_runtime.h>
#include <math.h>

// MaskedMultiHeadAttention (B=4, L=2048, D=1024), fp32 in/out, fp16-MFMA internals.
// d_out = [ out : 4*2048*1024 f32 | attn : 4*2048*2048 f32 ]
// ws (92MB): WQh WKh WVh WOh (f16) | qh | kh | vT | attn16 (f16); x reuses qh.

static constexpr int B_ = 4;
static constexpr int L_ = 2048;
static constexpr int D_ = 1024;

#define BM 128
#define BN 128
#define BKK 64   // K-step in elements (fp16)

typedef _Float16 f16x8 __attribute__((ext_vector_type(8)));
typedef float    f32x4 __attribute__((ext_vector_type(4)));
typedef short    s16x8 __attribute__((ext_vector_type(8)));
typedef unsigned short u16x4 __attribute__((ext_vector_type(4)));

typedef __attribute__((address_space(1))) const unsigned int GU32;
typedef __attribute__((address_space(3))) unsigned int LU32;

__device__ __forceinline__ void gload_lds16(const void* g, void* l) {
    __builtin_amdgcn_global_load_lds((GU32*)g, (LU32*)l, 16, 0, 0);
}

__device__ __forceinline__ short f2h_bits(float x) {
    union { _Float16 h; short s; } u;
    u.h = (_Float16)x;
    return u.s;
}

__device__ __forceinline__ s16x8 cvt8h(float4 a, float4 b) {
    union { _Float16 h[8]; s16x8 s; } u;
    u.h[0] = (_Float16)a.x; u.h[1] = (_Float16)a.y;
    u.h[2] = (_Float16)a.z; u.h[3] = (_Float16)a.w;
    u.h[4] = (_Float16)b.x; u.h[5] = (_Float16)b.y;
    u.h[6] = (_Float16)b.z; u.h[7] = (_Float16)b.w;
    return u.s;
}

// One K-step of MFMA work on a staged (A,B) LDS buffer pair.
__device__ __forceinline__ void compute_step(
    const short* __restrict__ As, const short* __restrict__ Bs,
    int wr, int wc, int lr, int lk, f32x4 (&acc)[4][4])
{
#pragma unroll
    for (int kk = 0; kk < 2; ++kk) {
        const int slotk = kk * 4 + lk;
        f16x8 a[4], b[4];
#pragma unroll
        for (int m = 0; m < 4; ++m) {
            const int r = wr * 64 + m * 16 + lr;
            a[m] = *(const f16x8*)&As[r * 64 + ((slotk ^ (r & 7)) << 3)];
        }
#pragma unroll
        for (int n = 0; n < 4; ++n) {
            const int c = wc * 64 + n * 16 + lr;
            b[n] = *(const f16x8*)&Bs[c * 64 + ((slotk ^ (c & 7)) << 3)];
        }
#pragma unroll
        for (int m = 0; m < 4; ++m)
#pragma unroll
            for (int n = 0; n < 4; ++n)
                acc[m][n] = __builtin_amdgcn_mfma_f32_16x16x32_f16(a[m], b[n], acc[m][n], 0, 0, 0);
    }
}

// C[M,N](+batch) = scale * A[M,K] @ Bt[N,K]^T, fp16 MFMA, fp32 accum.
// Double-buffered LDS, T3-minimum prefetch: stage(t+1) issued before compute(t),
// single vmcnt-drain barrier per iteration (2 for the AF32 reg-staged A path).
// AF32: A operand is fp32 (reg-staged + converted); else fp16 via global_load_lds.
// OMODE: 0 = store f16 row-major [M,N]; 1 = store f16 transposed (vT: [b][N][L_]);
//        2 = store f32 with scale (+ optional faithful-buggy tril mask).
// XCD-affinity swizzle: remap bx'=wg/gy, by'=wg%gy (gy%8==0) -> A-panel pinned
// to one XCD's L2.
template<int AF32, int OMODE>
__global__ __launch_bounds__(256) void hgemm(
    const void* __restrict__ Ap_, const short* __restrict__ Btp, void* __restrict__ Cp_,
    int M, int N, int K, long sA, long sB, long sC,
    float scale, int useMask, const int* __restrict__ mflag)
{
    __shared__ short As[2][BM * BKK];  // 2 x 16 KB
    __shared__ short Bs[2][BN * BKK];  // 2 x 16 KB

    const int t    = threadIdx.x;
    const int wid  = t >> 6;
    const int lane = t & 63;
    const int bz   = blockIdx.z;

    const int gx = gridDim.x, gy = gridDim.y;
    const int wg = blockIdx.y * gx + blockIdx.x;
    const int bm = (wg % gy) * BM;   // A-panel: fixed XCD
    const int bn = (wg / gy) * BN;

    const short* Bt = Btp + (long)bz * sB;
    const float* A32 = (const float*)Ap_ + (AF32 ? (long)bz * sA : 0);
    const short* A16 = (const short*)Ap_ + (AF32 ? 0 : (long)bz * sA);

    const int wr = wid >> 1, wc = wid & 1;   // wave 2x2 grid, each 64x64
    const int lr = lane & 15, lk = lane >> 4;

    const int srow  = t >> 3;  // staging row-in-issue (0..31)
    const int sslot = t & 7;   // staging 16B slot (0..7)

    const int ar = t >> 1, ah = t & 1;  // AF32 A staging: row, half-row

    f32x4 acc[4][4];
#pragma unroll
    for (int m = 0; m < 4; ++m)
#pragma unroll
        for (int n = 0; n < 4; ++n) acc[m][n] = (f32x4)0.f;

    const int nt = K / BKK;

    // ---- prologue: stage tile 0 into buffer 0 ----
    {
#pragma unroll
        for (int i = 0; i < 4; ++i) {
            const int rb = i * 32 + srow;
            const short* g = Bt + (long)(bn + rb) * K + ((sslot ^ (rb & 7)) << 3);
            gload_lds16(g, &Bs[0][i * 2048 + wid * 512]);
        }
        if constexpr (AF32) {
            const float* ga = A32 + (long)(bm + ar) * K + ah * 32;
            float4 f0[8];
#pragma unroll
            for (int j = 0; j < 8; ++j) f0[j] = ((const float4*)ga)[j];
#pragma unroll
            for (int q = 0; q < 4; ++q)
                *(s16x8*)&As[0][ar * 64 + ((((ah << 2) + q) ^ (ar & 7)) << 3)] =
                    cvt8h(f0[2 * q], f0[2 * q + 1]);
        } else {
#pragma unroll
            for (int i = 0; i < 4; ++i) {
                const int ra = i * 32 + srow;
                const short* g = A16 + (long)(bm + ra) * K + ((sslot ^ (ra & 7)) << 3);
                gload_lds16(g, &As[0][i * 2048 + wid * 512]);
            }
        }
    }
    __syncthreads();

    for (int ti = 0; ti < nt; ++ti) {
        const int cur = ti & 1, nxt = cur ^ 1;
        const int k1 = (ti + 1) * BKK;
        const bool hasNext = (ti + 1 < nt);

        float4 fn[8];
        if (hasNext) {
            // issue next tile's loads before compute (latency hides under MFMA)
#pragma unroll
            for (int i = 0; i < 4; ++i) {
                const int rb = i * 32 + srow;
                const short* g = Bt + (long)(bn + rb) * K + k1 + ((sslot ^ (rb & 7)) << 3);
                gload_lds16(g, &Bs[nxt][i * 2048 + wid * 512]);
            }
            if constexpr (AF32) {
                const float* ga = A32 + (long)(bm + ar) * K + k1 + ah * 32;
#pragma unroll
                for (int j = 0; j < 8; ++j) fn[j] = ((const float4*)ga)[j];
            } else {
#pragma unroll
                for (int i = 0; i < 4; ++i) {
                    const int ra = i * 32 + srow;
                    const short* g = A16 + (long)(bm + ra) * K + k1 + ((sslot ^ (ra & 7)) << 3);
                    gload_lds16(g, &As[nxt][i * 2048 + wid * 512]);
                }
            }
        }

        compute_step(&As[cur][0], &Bs[cur][0], wr, wc, lr, lk, acc);

        __syncthreads();  // drains vmcnt (prefetch arrived) + lgkm; cur fully consumed

        if constexpr (AF32) {
            if (hasNext) {
#pragma unroll
                for (int q = 0; q < 4; ++q)
                    *(s16x8*)&As[nxt][ar * 64 + ((((ah << 2) + q) ^ (ar & 7)) << 3)] =
                        cvt8h(fn[2 * q], fn[2 * q + 1]);
                __syncthreads();  // ds_writes visible before next compute
            }
        }
    }

    // ---- epilogue ----
    if constexpr (OMODE == 2) {
        float* C = (float*)Cp_ + (long)bz * sC;
        const bool msk = useMask && (mflag[0] != 0);
#pragma unroll
        for (int m = 0; m < 4; ++m) {
            const int r0 = bm + wr * 64 + m * 16 + lk * 4;
#pragma unroll
            for (int n = 0; n < 4; ++n) {
                const int c = bn + wc * 64 + n * 16 + lr;
#pragma unroll
                for (int g = 0; g < 4; ++g) {
                    float v = acc[m][n][g] * scale;
                    if (msk && c <= r0 + g) v = -INFINITY;
                    C[(long)(r0 + g) * N + c] = v;
                }
            }
        }
    } else if constexpr (OMODE == 0) {
        short* C = (short*)Cp_ + (long)bz * sC;
#pragma unroll
        for (int m = 0; m < 4; ++m) {
            const int r0 = bm + wr * 64 + m * 16 + lk * 4;
#pragma unroll
            for (int n = 0; n < 4; ++n) {
                const int c = bn + wc * 64 + n * 16 + lr;
#pragma unroll
                for (int g = 0; g < 4; ++g)
                    C[(long)(r0 + g) * N + c] = f2h_bits(acc[m][n][g]);
            }
        }
    } else {  // OMODE == 1: vT[b][N][L_], batch from global row
        short* C = (short*)Cp_;
#pragma unroll
        for (int m = 0; m < 4; ++m) {
            const int rg = bm + wr * 64 + m * 16 + lk * 4;
            const long rb = (long)(rg >> 11) * ((long)N * L_) + (rg & (L_ - 1));
#pragma unroll
            for (int n = 0; n < 4; ++n) {
                const int c = bn + wc * 64 + n * 16 + lr;
                u16x4 v;
#pragma unroll
                for (int g = 0; g < 4; ++g) v[g] = (unsigned short)f2h_bits(acc[m][n][g]);
                *(u16x4*)&C[rb + (long)c * L_] = v;
            }
        }
    }
}

// fp32 -> fp16 bit pattern, 8 elems/thread
__global__ __launch_bounds__(256) void cvt_f32_f16_k(
    const float* __restrict__ in, short* __restrict__ out, int n8)
{
    int i = blockIdx.x * 256 + threadIdx.x;
    if (i < n8) {
        float4 a = ((const float4*)in)[2 * i];
        float4 b = ((const float4*)in)[2 * i + 1];
        *(s16x8*)&out[i * 8] = cvt8h(a, b);
    }
}

// in-place row softmax over rows of length 2048; one block (256 thr) per row.
// Also writes a normalized fp16 copy (for the PV GEMM's gload_lds A-path).
__global__ __launch_bounds__(256) void softmax_rows_k(
    float* __restrict__ S, short* __restrict__ S16)
{
    const long row = blockIdx.x;
    float* p = S + row * (long)L_;
    short* p16 = S16 + row * (long)L_;
    const int tid = threadIdx.x;

    float4 v0 = ((const float4*)p)[tid];
    float4 v1 = ((const float4*)p)[tid + 256];

    float m = fmaxf(fmaxf(fmaxf(v0.x, v0.y), fmaxf(v0.z, v0.w)),
                    fmaxf(fmaxf(v1.x, v1.y), fmaxf(v1.z, v1.w)));
#pragma unroll
    for (int o = 32; o > 0; o >>= 1) m = fmaxf(m, __shfl_xor(m, o, 64));

    __shared__ float wmax[4], wsum[4];
    if ((tid & 63) == 0) wmax[tid >> 6] = m;
    __syncthreads();
    m = fmaxf(fmaxf(wmax[0], wmax[1]), fmaxf(wmax[2], wmax[3]));

    v0.x = expf(v0.x - m); v0.y = expf(v0.y - m);
    v0.z = expf(v0.z - m); v0.w = expf(v0.w - m);
    v1.x = expf(v1.x - m); v1.y = expf(v1.y - m);
    v1.z = expf(v1.z - m); v1.w = expf(v1.w - m);

    float s = v0.x + v0.y + v0.z + v0.w + v1.x + v1.y + v1.z + v1.w;
#pragma unroll
    for (int o = 32; o > 0; o >>= 1) s += __shfl_xor(s, o, 64);
    if ((tid & 63) == 0) wsum[tid >> 6] = s;
    __syncthreads();
    s = wsum[0] + wsum[1] + wsum[2] + wsum[3];

    const float inv = 1.f / s;
    v0.x *= inv; v0.y *= inv; v0.z *= inv; v0.w *= inv;
    v1.x *= inv; v1.y *= inv; v1.z *= inv; v1.w *= inv;
    ((float4*)p)[tid] = v0;
    ((float4*)p)[tid + 256] = v1;

    union { _Float16 h[4]; u16x4 u; } h0, h1;
    h0.h[0] = (_Float16)v0.x; h0.h[1] = (_Float16)v0.y;
    h0.h[2] = (_Float16)v0.z; h0.h[3] = (_Float16)v0.w;
    h1.h[0] = (_Float16)v1.x; h1.h[1] = (_Float16)v1.y;
    h1.h[2] = (_Float16)v1.z; h1.h[3] = (_Float16)v1.w;
    ((u16x4*)p16)[tid] = h0.u;
    ((u16x4*)p16)[tid + 256] = h1.u;
}

extern "C" void kernel_launch(void* const* d_in, const int* in_sizes, int n_in,
                              void* d_out, int out_size, void* d_ws, size_t ws_size,
                              hipStream_t stream) {
    const float* Q   = (const float*)d_in[0];
    const float* K   = (const float*)d_in[1];
    const float* V   = (const float*)d_in[2];
    const float* W_Q = (const float*)d_in[3];
    const float* W_K = (const float*)d_in[4];
    const float* W_V = (const float*)d_in[5];
    const float* W_O = (const float*)d_in[6];
    const int* masked = (const int*)d_in[7];

    float* out  = (float*)d_out;                    // [4,2048,1024]
    float* attn = out + (size_t)B_ * L_ * D_;       // [4,2048,2048]

    // ws layout (shorts): 8MB weights | qh 16.8 | kh 16.8 | vT 16.8 | attn16 33.6
    short* wq = (short*)d_ws;
    short* wk = wq + (size_t)D_ * D_;
    short* wv = wk + (size_t)D_ * D_;
    short* wo = wv + (size_t)D_ * D_;
    short* qh = wo + (size_t)D_ * D_;               // [8192,1024] f16
    short* kh = qh + (size_t)B_ * L_ * D_;
    short* vT = kh + (size_t)B_ * L_ * D_;          // [4][1024][2048] f16
    short* attn16 = vT + (size_t)B_ * L_ * D_;      // [4][2048][2048] f16
    short* xh = qh;                                 // reuse after scores

    const long SLD = (long)L_ * D_;
    const long SLL = (long)L_ * L_;

    // 1) weights fp32 -> fp16
    const int n8 = D_ * D_ / 8;
    cvt_f32_f16_k<<<dim3(n8 / 256), 256, 0, stream>>>(W_Q, wq, n8);
    cvt_f32_f16_k<<<dim3(n8 / 256), 256, 0, stream>>>(W_K, wk, n8);
    cvt_f32_f16_k<<<dim3(n8 / 256), 256, 0, stream>>>(W_V, wv, n8);
    cvt_f32_f16_k<<<dim3(n8 / 256), 256, 0, stream>>>(W_O, wo, n8);

    // 2) projections (A = fp32 inputs, reg-staged convert)
    dim3 gproj(D_ / BN, (B_ * L_) / BM, 1);
    hgemm<1, 0><<<gproj, 256, 0, stream>>>(Q, wq, qh, B_ * L_, D_, D_, 0, 0, 0, 1.f, 0, masked);
    hgemm<1, 0><<<gproj, 256, 0, stream>>>(K, wk, kh, B_ * L_, D_, D_, 0, 0, 0, 1.f, 0, masked);
    hgemm<1, 1><<<gproj, 256, 0, stream>>>(V, wv, vT, B_ * L_, D_, D_, 0, 0, 0, 1.f, 0, masked);

    // 3) scores = q @ k^T / 8 -> fp32 into attn slot (+ faithful mask)
    dim3 gsc(L_ / BN, L_ / BM, B_);
    hgemm<0, 2><<<gsc, 256, 0, stream>>>(qh, kh, attn, L_, L_, D_, SLD, SLD, SLL,
                                         0.125f, 1, masked);

    // 4) softmax rows, in place (fp32) + fp16 copy for PV
    softmax_rows_k<<<dim3(B_ * L_), 256, 0, stream>>>(attn, attn16);

    // 5) x = attn16 @ v  (A fp16 via gload_lds; B = vT) -> f16 x
    dim3 gav(D_ / BN, L_ / BM, B_);
    hgemm<0, 0><<<gav, 256, 0, stream>>>(attn16, vT, xh, L_, D_, L_, SLL, SLD, SLD,
                                         1.f, 0, masked);

    // 6) out = x @ W_O^T -> fp32
    hgemm<0, 2><<<gproj, 256, 0, stream>>>(xh, wo, out, B_ * L_, D_, D_, 0, 0, 0,
                                           1.f, 0, masked);
}

// Round 8
// 293.949 us; speedup vs baseline: 1.1183x; 1.1183x over previous
//
#include <hip/hip_runtime.h>
#include <math.h>

// MaskedMultiHeadAttention (B=4, L=2048, D=1024), fp32 in/out, fp16-MFMA internals.
// d_out = [ out : 4*2048*1024 f32 | attn : 4*2048*2048 f32 ]
// ws (92MB): wq wk wv wo (f16) | qh | kh | vT | attn16 (f16); x reuses qh.
// Inner loop = round-6 structure (single LDS buffer, 2 barriers/K-step) — the
// dbuf prefetch variant regressed (MfmaUtil & VALUBusy both ~9.5%, latency-bound;
// compiler serializes in-flight global_load_lds against ds_reads).
// This round: QKV projections share ONE dispatch (blockIdx.z selects input) ->
// 1536 blocks (5 blocks/CU, LDS-capped) vs 3 x 512-block (2/CU) launches.

static constexpr int B_ = 4;
static constexpr int L_ = 2048;
static constexpr int D_ = 1024;

#define BM 128
#define BN 128
#define BKK 64   // K-step in elements (fp16)

typedef _Float16 f16x8 __attribute__((ext_vector_type(8)));
typedef float    f32x4 __attribute__((ext_vector_type(4)));
typedef short    s16x8 __attribute__((ext_vector_type(8)));
typedef unsigned short u16x4 __attribute__((ext_vector_type(4)));

typedef __attribute__((address_space(1))) const unsigned int GU32;
typedef __attribute__((address_space(3))) unsigned int LU32;

__device__ __forceinline__ void gload_lds16(const void* g, void* l) {
    __builtin_amdgcn_global_load_lds((GU32*)g, (LU32*)l, 16, 0, 0);
}

__device__ __forceinline__ short f2h_bits(float x) {
    union { _Float16 h; short s; } u;
    u.h = (_Float16)x;
    return u.s;
}

__device__ __forceinline__ s16x8 cvt8h(float4 a, float4 b) {
    union { _Float16 h[8]; s16x8 s; } u;
    u.h[0] = (_Float16)a.x; u.h[1] = (_Float16)a.y;
    u.h[2] = (_Float16)a.z; u.h[3] = (_Float16)a.w;
    u.h[4] = (_Float16)b.x; u.h[5] = (_Float16)b.y;
    u.h[6] = (_Float16)b.z; u.h[7] = (_Float16)b.w;
    return u.s;
}

// One K-step of MFMA work on staged (A,B) LDS tiles.
__device__ __forceinline__ void compute_step(
    const short* __restrict__ As, const short* __restrict__ Bs,
    int wr, int wc, int lr, int lk, f32x4 (&acc)[4][4])
{
#pragma unroll
    for (int kk = 0; kk < 2; ++kk) {
        const int slotk = kk * 4 + lk;
        f16x8 a[4], b[4];
#pragma unroll
        for (int m = 0; m < 4; ++m) {
            const int r = wr * 64 + m * 16 + lr;
            a[m] = *(const f16x8*)&As[r * 64 + ((slotk ^ (r & 7)) << 3)];
        }
#pragma unroll
        for (int n = 0; n < 4; ++n) {
            const int c = wc * 64 + n * 16 + lr;
            b[n] = *(const f16x8*)&Bs[c * 64 + ((slotk ^ (c & 7)) << 3)];
        }
#pragma unroll
        for (int m = 0; m < 4; ++m)
#pragma unroll
            for (int n = 0; n < 4; ++n)
                acc[m][n] = __builtin_amdgcn_mfma_f32_16x16x32_f16(a[m], b[n], acc[m][n], 0, 0, 0);
    }
}

// ---------------- fused QKV projection ----------------
// grid (8, 64, 3): z selects (A, W, out). M=8192, N=1024, K=1024. A is fp32.
// z=0: qh = Q@wq^T (f16 [M,N]); z=1: kh = K@wk^T; z=2: vT[b][n][row] = V@wv^T.
__global__ __launch_bounds__(256) void proj_qkv(
    const float* __restrict__ Qp, const float* __restrict__ Kp, const float* __restrict__ Vp,
    const short* __restrict__ wq, const short* __restrict__ wk, const short* __restrict__ wv,
    short* __restrict__ qh, short* __restrict__ kh, short* __restrict__ vT)
{
    __shared__ short As[BM * BKK];  // 16 KB
    __shared__ short Bs[BN * BKK];  // 16 KB

    const int t    = threadIdx.x;
    const int wid  = t >> 6;
    const int lane = t & 63;
    const int bz   = blockIdx.z;

    const float* A32 = (bz == 0) ? Qp : (bz == 1) ? Kp : Vp;
    const short* Bt  = (bz == 0) ? wq : (bz == 1) ? wk : wv;

    const int gx = gridDim.x, gy = gridDim.y;
    const int wg = blockIdx.y * gx + blockIdx.x;
    const int bm = (wg % gy) * BM;   // A-panel pinned to one XCD (gy%8==0)
    const int bn = (wg / gy) * BN;

    const int wr = wid >> 1, wc = wid & 1;
    const int lr = lane & 15, lk = lane >> 4;
    const int srow  = t >> 3, sslot = t & 7;
    const int ar = t >> 1, ah = t & 1;
    const int K = D_;

    f32x4 acc[4][4];
#pragma unroll
    for (int m = 0; m < 4; ++m)
#pragma unroll
        for (int n = 0; n < 4; ++n) acc[m][n] = (f32x4)0.f;

    for (int k0 = 0; k0 < K; k0 += BKK) {
        __syncthreads();
#pragma unroll
        for (int i = 0; i < 4; ++i) {
            const int rb = i * 32 + srow;
            const short* g = Bt + (long)(bn + rb) * K + k0 + ((sslot ^ (rb & 7)) << 3);
            gload_lds16(g, &Bs[i * 2048 + wid * 512]);
        }
        {
            const float* ga = A32 + (long)(bm + ar) * K + k0 + ah * 32;
            float4 f[8];
#pragma unroll
            for (int j = 0; j < 8; ++j) f[j] = ((const float4*)ga)[j];
#pragma unroll
            for (int q = 0; q < 4; ++q)
                *(s16x8*)&As[ar * 64 + ((((ah << 2) + q) ^ (ar & 7)) << 3)] =
                    cvt8h(f[2 * q], f[2 * q + 1]);
        }
        __syncthreads();
        compute_step(As, Bs, wr, wc, lr, lk, acc);
    }

    const int N = D_;
    if (bz < 2) {
        short* C = (bz == 0) ? qh : kh;
#pragma unroll
        for (int m = 0; m < 4; ++m) {
            const int r0 = bm + wr * 64 + m * 16 + lk * 4;
#pragma unroll
            for (int n = 0; n < 4; ++n) {
                const int c = bn + wc * 64 + n * 16 + lr;
#pragma unroll
                for (int g = 0; g < 4; ++g)
                    C[(long)(r0 + g) * N + c] = f2h_bits(acc[m][n][g]);
            }
        }
    } else {
#pragma unroll
        for (int m = 0; m < 4; ++m) {
            const int rg = bm + wr * 64 + m * 16 + lk * 4;
            const long rb = (long)(rg >> 11) * ((long)N * L_) + (rg & (L_ - 1));
#pragma unroll
            for (int n = 0; n < 4; ++n) {
                const int c = bn + wc * 64 + n * 16 + lr;
                u16x4 v;
#pragma unroll
                for (int g = 0; g < 4; ++g) v[g] = (unsigned short)f2h_bits(acc[m][n][g]);
                *(u16x4*)&vT[rb + (long)c * L_] = v;
            }
        }
    }
}

// ---------------- generic f16 GEMM (round-6 structure) ----------------
// C[M,N](+batch) = scale * A[M,K] @ Bt[N,K]^T; A fp16 via global_load_lds.
// OMODE: 0 = f16 [M,N]; 2 = f32 with scale (+ faithful-buggy tril mask).
template<int OMODE>
__global__ __launch_bounds__(256) void hgemm(
    const short* __restrict__ A16p, const short* __restrict__ Btp, void* __restrict__ Cp_,
    int M, int N, int K, long sA, long sB, long sC,
    float scale, int useMask, const int* __restrict__ mflag)
{
    __shared__ short As[BM * BKK];
    __shared__ short Bs[BN * BKK];

    const int t    = threadIdx.x;
    const int wid  = t >> 6;
    const int lane = t & 63;
    const int bz   = blockIdx.z;

    const int gx = gridDim.x, gy = gridDim.y;
    const int wg = blockIdx.y * gx + blockIdx.x;
    const int bm = (wg % gy) * BM;
    const int bn = (wg / gy) * BN;

    const short* Bt  = Btp + (long)bz * sB;
    const short* A16 = A16p + (long)bz * sA;

    const int wr = wid >> 1, wc = wid & 1;
    const int lr = lane & 15, lk = lane >> 4;
    const int srow = t >> 3, sslot = t & 7;

    f32x4 acc[4][4];
#pragma unroll
    for (int m = 0; m < 4; ++m)
#pragma unroll
        for (int n = 0; n < 4; ++n) acc[m][n] = (f32x4)0.f;

    for (int k0 = 0; k0 < K; k0 += BKK) {
        __syncthreads();
#pragma unroll
        for (int i = 0; i < 4; ++i) {
            const int rb = i * 32 + srow;
            const short* g = Bt + (long)(bn + rb) * K + k0 + ((sslot ^ (rb & 7)) << 3);
            gload_lds16(g, &Bs[i * 2048 + wid * 512]);
        }
#pragma unroll
        for (int i = 0; i < 4; ++i) {
            const int ra = i * 32 + srow;
            const short* g = A16 + (long)(bm + ra) * K + k0 + ((sslot ^ (ra & 7)) << 3);
            gload_lds16(g, &As[i * 2048 + wid * 512]);
        }
        __syncthreads();
        compute_step(As, Bs, wr, wc, lr, lk, acc);
    }

    if constexpr (OMODE == 2) {
        float* C = (float*)Cp_ + (long)bz * sC;
        const bool msk = useMask && (mflag[0] != 0);
#pragma unroll
        for (int m = 0; m < 4; ++m) {
            const int r0 = bm + wr * 64 + m * 16 + lk * 4;
#pragma unroll
            for (int n = 0; n < 4; ++n) {
                const int c = bn + wc * 64 + n * 16 + lr;
#pragma unroll
                for (int g = 0; g < 4; ++g) {
                    float v = acc[m][n][g] * scale;
                    if (msk && c <= r0 + g) v = -INFINITY;
                    C[(long)(r0 + g) * N + c] = v;
                }
            }
        }
    } else {
        short* C = (short*)Cp_ + (long)bz * sC;
#pragma unroll
        for (int m = 0; m < 4; ++m) {
            const int r0 = bm + wr * 64 + m * 16 + lk * 4;
#pragma unroll
            for (int n = 0; n < 4; ++n) {
                const int c = bn + wc * 64 + n * 16 + lr;
#pragma unroll
                for (int g = 0; g < 4; ++g)
                    C[(long)(r0 + g) * N + c] = f2h_bits(acc[m][n][g]);
            }
        }
    }
}

// fp32 -> fp16 for the 4 weight matrices in one dispatch (grid.y selects W)
__global__ __launch_bounds__(256) void cvt_w4_k(
    const float* __restrict__ W_Q, const float* __restrict__ W_K,
    const float* __restrict__ W_V, const float* __restrict__ W_O,
    short* __restrict__ dst)
{
    const int w = blockIdx.y;
    const float* src = (w == 0) ? W_Q : (w == 1) ? W_K : (w == 2) ? W_V : W_O;
    short* out = dst + (size_t)w * D_ * D_;
    const int i = blockIdx.x * 256 + threadIdx.x;
    float4 a = ((const float4*)src)[2 * i];
    float4 b = ((const float4*)src)[2 * i + 1];
    *(s16x8*)&out[i * 8] = cvt8h(a, b);
}

// in-place row softmax (rows of 2048) + normalized fp16 copy for PV
__global__ __launch_bounds__(256) void softmax_rows_k(
    float* __restrict__ S, short* __restrict__ S16)
{
    const long row = blockIdx.x;
    float* p = S + row * (long)L_;
    short* p16 = S16 + row * (long)L_;
    const int tid = threadIdx.x;

    float4 v0 = ((const float4*)p)[tid];
    float4 v1 = ((const float4*)p)[tid + 256];

    float m = fmaxf(fmaxf(fmaxf(v0.x, v0.y), fmaxf(v0.z, v0.w)),
                    fmaxf(fmaxf(v1.x, v1.y), fmaxf(v1.z, v1.w)));
#pragma unroll
    for (int o = 32; o > 0; o >>= 1) m = fmaxf(m, __shfl_xor(m, o, 64));

    __shared__ float wmax[4], wsum[4];
    if ((tid & 63) == 0) wmax[tid >> 6] = m;
    __syncthreads();
    m = fmaxf(fmaxf(wmax[0], wmax[1]), fmaxf(wmax[2], wmax[3]));

    v0.x = expf(v0.x - m); v0.y = expf(v0.y - m);
    v0.z = expf(v0.z - m); v0.w = expf(v0.w - m);
    v1.x = expf(v1.x - m); v1.y = expf(v1.y - m);
    v1.z = expf(v1.z - m); v1.w = expf(v1.w - m);

    float s = v0.x + v0.y + v0.z + v0.w + v1.x + v1.y + v1.z + v1.w;
#pragma unroll
    for (int o = 32; o > 0; o >>= 1) s += __shfl_xor(s, o, 64);
    if ((tid & 63) == 0) wsum[tid >> 6] = s;
    __syncthreads();
    s = wsum[0] + wsum[1] + wsum[2] + wsum[3];

    const float inv = 1.f / s;
    v0.x *= inv; v0.y *= inv; v0.z *= inv; v0.w *= inv;
    v1.x *= inv; v1.y *= inv; v1.z *= inv; v1.w *= inv;
    ((float4*)p)[tid] = v0;
    ((float4*)p)[tid + 256] = v1;

    union { _Float16 h[4]; u16x4 u; } h0, h1;
    h0.h[0] = (_Float16)v0.x; h0.h[1] = (_Float16)v0.y;
    h0.h[2] = (_Float16)v0.z; h0.h[3] = (_Float16)v0.w;
    h1.h[0] = (_Float16)v1.x; h1.h[1] = (_Float16)v1.y;
    h1.h[2] = (_Float16)v1.z; h1.h[3] = (_Float16)v1.w;
    ((u16x4*)p16)[tid] = h0.u;
    ((u16x4*)p16)[tid + 256] = h1.u;
}

extern "C" void kernel_launch(void* const* d_in, const int* in_sizes, int n_in,
                              void* d_out, int out_size, void* d_ws, size_t ws_size,
                              hipStream_t stream) {
    const float* Q   = (const float*)d_in[0];
    const float* K   = (const float*)d_in[1];
    const float* V   = (const float*)d_in[2];
    const float* W_Q = (const float*)d_in[3];
    const float* W_K = (const float*)d_in[4];
    const float* W_V = (const float*)d_in[5];
    const float* W_O = (const float*)d_in[6];
    const int* masked = (const int*)d_in[7];

    float* out  = (float*)d_out;                    // [4,2048,1024]
    float* attn = out + (size_t)B_ * L_ * D_;       // [4,2048,2048]

    // ws layout (shorts): 8MB weights | qh 16.8 | kh 16.8 | vT 16.8 | attn16 33.6
    short* wq = (short*)d_ws;
    short* wk = wq + (size_t)D_ * D_;
    short* wv = wk + (size_t)D_ * D_;
    short* wo = wv + (size_t)D_ * D_;
    short* qh = wo + (size_t)D_ * D_;               // [8192,1024] f16
    short* kh = qh + (size_t)B_ * L_ * D_;
    short* vT = kh + (size_t)B_ * L_ * D_;          // [4][1024][2048] f16
    short* attn16 = vT + (size_t)B_ * L_ * D_;      // [4][2048][2048] f16
    short* xh = qh;                                 // reuse after scores

    const long SLD = (long)L_ * D_;
    const long SLL = (long)L_ * L_;

    // 1) weights fp32 -> fp16 (one dispatch)
    cvt_w4_k<<<dim3(D_ * D_ / 8 / 256, 4), 256, 0, stream>>>(W_Q, W_K, W_V, W_O, wq);

    // 2) fused QKV projections: one dispatch, 1536 blocks
    proj_qkv<<<dim3(D_ / BN, (B_ * L_) / BM, 3), 256, 0, stream>>>(
        Q, K, V, wq, wk, wv, qh, kh, vT);

    // 3) scores = q @ k^T / 8 -> fp32 into attn slot (+ faithful mask)
    dim3 gsc(L_ / BN, L_ / BM, B_);
    hgemm<2><<<gsc, 256, 0, stream>>>(qh, kh, attn, L_, L_, D_, SLD, SLD, SLL,
                                      0.125f, 1, masked);

    // 4) softmax rows, in place (fp32) + fp16 copy for PV
    softmax_rows_k<<<dim3(B_ * L_), 256, 0, stream>>>(attn, attn16);

    // 5) x = attn16 @ vT -> f16 x
    dim3 gav(D_ / BN, L_ / BM, B_);
    hgemm<0><<<gav, 256, 0, stream>>>(attn16, vT, xh, L_, D_, L_, SLL, SLD, SLD,
                                      1.f, 0, masked);

    // 6) out = x @ W_O^T -> fp32
    dim3 gproj(D_ / BN, (B_ * L_) / BM, 1);
    hgemm<2><<<gproj, 256, 0, stream>>>(xh, wo, out, B_ * L_, D_, D_, 0, 0, 0,
                                        1.f, 0, masked);
}

// Round 9
// 258.586 us; speedup vs baseline: 1.2712x; 1.1368x over previous
//
#include <hip/hip_runtime.h>
#include <math.h>

// MaskedMultiHeadAttention (B=4, L=2048, D=1024), fp32 in/out, fp16-MFMA internals.
// d_out = [ out : 4*2048*1024 f32 | attn : 4*2048*2048 f32 ]
// ws (92MB): wq wk wv wo (f16) | qh | kh | vT | attn16 (f16); x reuses qh.
// fp16 copies of Q/K/V (50.3MB) are stashed in d_out's attn region (67MB):
// they die when proj_qkv completes, before the scores GEMM writes attn.
// Inner loop = round-6 structure (single LDS buffer, 2 barriers/K-step); the
// explicit dbuf prefetch variant regressed (latency-bound, round 7).

static constexpr int B_ = 4;
static constexpr int L_ = 2048;
static constexpr int D_ = 1024;

#define BM 128
#define BN 128
#define BKK 64   // K-step in elements (fp16)

typedef _Float16 f16x8 __attribute__((ext_vector_type(8)));
typedef float    f32x4 __attribute__((ext_vector_type(4)));
typedef short    s16x8 __attribute__((ext_vector_type(8)));
typedef unsigned short u16x4 __attribute__((ext_vector_type(4)));

typedef __attribute__((address_space(1))) const unsigned int GU32;
typedef __attribute__((address_space(3))) unsigned int LU32;

__device__ __forceinline__ void gload_lds16(const void* g, void* l) {
    __builtin_amdgcn_global_load_lds((GU32*)g, (LU32*)l, 16, 0, 0);
}

__device__ __forceinline__ short f2h_bits(float x) {
    union { _Float16 h; short s; } u;
    u.h = (_Float16)x;
    return u.s;
}

__device__ __forceinline__ s16x8 cvt8h(float4 a, float4 b) {
    union { _Float16 h[8]; s16x8 s; } u;
    u.h[0] = (_Float16)a.x; u.h[1] = (_Float16)a.y;
    u.h[2] = (_Float16)a.z; u.h[3] = (_Float16)a.w;
    u.h[4] = (_Float16)b.x; u.h[5] = (_Float16)b.y;
    u.h[6] = (_Float16)b.z; u.h[7] = (_Float16)b.w;
    return u.s;
}

// One K-step of MFMA work on staged (A,B) LDS tiles.
__device__ __forceinline__ void compute_step(
    const short* __restrict__ As, const short* __restrict__ Bs,
    int wr, int wc, int lr, int lk, f32x4 (&acc)[4][4])
{
#pragma unroll
    for (int kk = 0; kk < 2; ++kk) {
        const int slotk = kk * 4 + lk;
        f16x8 a[4], b[4];
#pragma unroll
        for (int m = 0; m < 4; ++m) {
            const int r = wr * 64 + m * 16 + lr;
            a[m] = *(const f16x8*)&As[r * 64 + ((slotk ^ (r & 7)) << 3)];
        }
#pragma unroll
        for (int n = 0; n < 4; ++n) {
            const int c = wc * 64 + n * 16 + lr;
            b[n] = *(const f16x8*)&Bs[c * 64 + ((slotk ^ (c & 7)) << 3)];
        }
#pragma unroll
        for (int m = 0; m < 4; ++m)
#pragma unroll
            for (int n = 0; n < 4; ++n)
                acc[m][n] = __builtin_amdgcn_mfma_f32_16x16x32_f16(a[m], b[n], acc[m][n], 0, 0, 0);
    }
}

// ---------------- fused QKV projection (pure f16 both sides) ----------------
// grid (8, 64, 3): z selects (A16, W, out). M=8192, N=1024, K=1024.
// z=0: qh = qf@wq^T (f16 [M,N]); z=1: kh = kf@wk^T; z=2: vT[b][n][row].
__global__ __launch_bounds__(256) void proj_qkv(
    const short* __restrict__ qf, const short* __restrict__ kf, const short* __restrict__ vf,
    const short* __restrict__ wq, const short* __restrict__ wk, const short* __restrict__ wv,
    short* __restrict__ qh, short* __restrict__ kh, short* __restrict__ vT)
{
    __shared__ short As[BM * BKK];  // 16 KB
    __shared__ short Bs[BN * BKK];  // 16 KB

    const int t    = threadIdx.x;
    const int wid  = t >> 6;
    const int lane = t & 63;
    const int bz   = blockIdx.z;

    const short* A16 = (bz == 0) ? qf : (bz == 1) ? kf : vf;
    const short* Bt  = (bz == 0) ? wq : (bz == 1) ? wk : wv;

    const int gx = gridDim.x, gy = gridDim.y;
    const int wg = blockIdx.y * gx + blockIdx.x;
    const int bm = (wg % gy) * BM;   // A-panel pinned to one XCD (gy%8==0)
    const int bn = (wg / gy) * BN;

    const int wr = wid >> 1, wc = wid & 1;
    const int lr = lane & 15, lk = lane >> 4;
    const int srow = t >> 3, sslot = t & 7;
    const int K = D_;

    f32x4 acc[4][4];
#pragma unroll
    for (int m = 0; m < 4; ++m)
#pragma unroll
        for (int n = 0; n < 4; ++n) acc[m][n] = (f32x4)0.f;

    for (int k0 = 0; k0 < K; k0 += BKK) {
        __syncthreads();
#pragma unroll
        for (int i = 0; i < 4; ++i) {
            const int rb = i * 32 + srow;
            const short* g = Bt + (long)(bn + rb) * K + k0 + ((sslot ^ (rb & 7)) << 3);
            gload_lds16(g, &Bs[i * 2048 + wid * 512]);
        }
#pragma unroll
        for (int i = 0; i < 4; ++i) {
            const int ra = i * 32 + srow;
            const short* g = A16 + (long)(bm + ra) * K + k0 + ((sslot ^ (ra & 7)) << 3);
            gload_lds16(g, &As[i * 2048 + wid * 512]);
        }
        __syncthreads();
        compute_step(As, Bs, wr, wc, lr, lk, acc);
    }

    const int N = D_;
    if (bz < 2) {
        short* C = (bz == 0) ? qh : kh;
#pragma unroll
        for (int m = 0; m < 4; ++m) {
            const int r0 = bm + wr * 64 + m * 16 + lk * 4;
#pragma unroll
            for (int n = 0; n < 4; ++n) {
                const int c = bn + wc * 64 + n * 16 + lr;
#pragma unroll
                for (int g = 0; g < 4; ++g)
                    C[(long)(r0 + g) * N + c] = f2h_bits(acc[m][n][g]);
            }
        }
    } else {
#pragma unroll
        for (int m = 0; m < 4; ++m) {
            const int rg = bm + wr * 64 + m * 16 + lk * 4;
            const long rb = (long)(rg >> 11) * ((long)N * L_) + (rg & (L_ - 1));
#pragma unroll
            for (int n = 0; n < 4; ++n) {
                const int c = bn + wc * 64 + n * 16 + lr;
                u16x4 v;
#pragma unroll
                for (int g = 0; g < 4; ++g) v[g] = (unsigned short)f2h_bits(acc[m][n][g]);
                *(u16x4*)&vT[rb + (long)c * L_] = v;
            }
        }
    }
}

// ---------------- generic f16 GEMM (round-6 structure) ----------------
// C[M,N](+batch) = scale * A[M,K] @ Bt[N,K]^T; A fp16 via global_load_lds.
// OMODE: 0 = f16 [M,N]; 2 = f32 with scale (+ faithful-buggy tril mask).
template<int OMODE>
__global__ __launch_bounds__(256) void hgemm(
    const short* __restrict__ A16p, const short* __restrict__ Btp, void* __restrict__ Cp_,
    int M, int N, int K, long sA, long sB, long sC,
    float scale, int useMask, const int* __restrict__ mflag)
{
    __shared__ short As[BM * BKK];
    __shared__ short Bs[BN * BKK];

    const int t    = threadIdx.x;
    const int wid  = t >> 6;
    const int lane = t & 63;
    const int bz   = blockIdx.z;

    const int gx = gridDim.x, gy = gridDim.y;
    const int wg = blockIdx.y * gx + blockIdx.x;
    const int bm = (wg % gy) * BM;
    const int bn = (wg / gy) * BN;

    const short* Bt  = Btp + (long)bz * sB;
    const short* A16 = A16p + (long)bz * sA;

    const int wr = wid >> 1, wc = wid & 1;
    const int lr = lane & 15, lk = lane >> 4;
    const int srow = t >> 3, sslot = t & 7;

    f32x4 acc[4][4];
#pragma unroll
    for (int m = 0; m < 4; ++m)
#pragma unroll
        for (int n = 0; n < 4; ++n) acc[m][n] = (f32x4)0.f;

    for (int k0 = 0; k0 < K; k0 += BKK) {
        __syncthreads();
#pragma unroll
        for (int i = 0; i < 4; ++i) {
            const int rb = i * 32 + srow;
            const short* g = Bt + (long)(bn + rb) * K + k0 + ((sslot ^ (rb & 7)) << 3);
            gload_lds16(g, &Bs[i * 2048 + wid * 512]);
        }
#pragma unroll
        for (int i = 0; i < 4; ++i) {
            const int ra = i * 32 + srow;
            const short* g = A16 + (long)(bm + ra) * K + k0 + ((sslot ^ (ra & 7)) << 3);
            gload_lds16(g, &As[i * 2048 + wid * 512]);
        }
        __syncthreads();
        compute_step(As, Bs, wr, wc, lr, lk, acc);
    }

    if constexpr (OMODE == 2) {
        float* C = (float*)Cp_ + (long)bz * sC;
        const bool msk = useMask && (mflag[0] != 0);
#pragma unroll
        for (int m = 0; m < 4; ++m) {
            const int r0 = bm + wr * 64 + m * 16 + lk * 4;
#pragma unroll
            for (int n = 0; n < 4; ++n) {
                const int c = bn + wc * 64 + n * 16 + lr;
#pragma unroll
                for (int g = 0; g < 4; ++g) {
                    float v = acc[m][n][g] * scale;
                    if (msk && c <= r0 + g) v = -INFINITY;
                    C[(long)(r0 + g) * N + c] = v;
                }
            }
        }
    } else {
        short* C = (short*)Cp_ + (long)bz * sC;
#pragma unroll
        for (int m = 0; m < 4; ++m) {
            const int r0 = bm + wr * 64 + m * 16 + lk * 4;
#pragma unroll
            for (int n = 0; n < 4; ++n) {
                const int c = bn + wc * 64 + n * 16 + lr;
#pragma unroll
                for (int g = 0; g < 4; ++g)
                    C[(long)(r0 + g) * N + c] = f2h_bits(acc[m][n][g]);
            }
        }
    }
}

// fp32 -> fp16 for the 4 weight matrices in one dispatch (grid.y selects W)
__global__ __launch_bounds__(256) void cvt_w4_k(
    const float* __restrict__ W_Q, const float* __restrict__ W_K,
    const float* __restrict__ W_V, const float* __restrict__ W_O,
    short* __restrict__ dst)
{
    const int w = blockIdx.y;
    const float* src = (w == 0) ? W_Q : (w == 1) ? W_K : (w == 2) ? W_V : W_O;
    short* out = dst + (size_t)w * D_ * D_;
    const int i = blockIdx.x * 256 + threadIdx.x;
    float4 a = ((const float4*)src)[2 * i];
    float4 b = ((const float4*)src)[2 * i + 1];
    *(s16x8*)&out[i * 8] = cvt8h(a, b);
}

// fp32 -> fp16 for Q,K,V in one dispatch (grid.y selects tensor)
__global__ __launch_bounds__(256) void cvt_qkv_k(
    const float* __restrict__ Q, const float* __restrict__ K,
    const float* __restrict__ V, short* __restrict__ dst)
{
    const int w = blockIdx.y;
    const float* src = (w == 0) ? Q : (w == 1) ? K : V;
    short* out = dst + (size_t)w * B_ * L_ * D_;
    const int i = blockIdx.x * 256 + threadIdx.x;
    float4 a = ((const float4*)src)[2 * i];
    float4 b = ((const float4*)src)[2 * i + 1];
    *(s16x8*)&out[i * 8] = cvt8h(a, b);
}

// in-place row softmax (rows of 2048) + normalized fp16 copy for PV
__global__ __launch_bounds__(256) void softmax_rows_k(
    float* __restrict__ S, short* __restrict__ S16)
{
    const long row = blockIdx.x;
    float* p = S + row * (long)L_;
    short* p16 = S16 + row * (long)L_;
    const int tid = threadIdx.x;

    float4 v0 = ((const float4*)p)[tid];
    float4 v1 = ((const float4*)p)[tid + 256];

    float m = fmaxf(fmaxf(fmaxf(v0.x, v0.y), fmaxf(v0.z, v0.w)),
                    fmaxf(fmaxf(v1.x, v1.y), fmaxf(v1.z, v1.w)));
#pragma unroll
    for (int o = 32; o > 0; o >>= 1) m = fmaxf(m, __shfl_xor(m, o, 64));

    __shared__ float wmax[4], wsum[4];
    if ((tid & 63) == 0) wmax[tid >> 6] = m;
    __syncthreads();
    m = fmaxf(fmaxf(wmax[0], wmax[1]), fmaxf(wmax[2], wmax[3]));

    v0.x = expf(v0.x - m); v0.y = expf(v0.y - m);
    v0.z = expf(v0.z - m); v0.w = expf(v0.w - m);
    v1.x = expf(v1.x - m); v1.y = expf(v1.y - m);
    v1.z = expf(v1.z - m); v1.w = expf(v1.w - m);

    float s = v0.x + v0.y + v0.z + v0.w + v1.x + v1.y + v1.z + v1.w;
#pragma unroll
    for (int o = 32; o > 0; o >>= 1) s += __shfl_xor(s, o, 64);
    if ((tid & 63) == 0) wsum[tid >> 6] = s;
    __syncthreads();
    s = wsum[0] + wsum[1] + wsum[2] + wsum[3];

    const float inv = 1.f / s;
    v0.x *= inv; v0.y *= inv; v0.z *= inv; v0.w *= inv;
    v1.x *= inv; v1.y *= inv; v1.z *= inv; v1.w *= inv;
    ((float4*)p)[tid] = v0;
    ((float4*)p)[tid + 256] = v1;

    union { _Float16 h[4]; u16x4 u; } h0, h1;
    h0.h[0] = (_Float16)v0.x; h0.h[1] = (_Float16)v0.y;
    h0.h[2] = (_Float16)v0.z; h0.h[3] = (_Float16)v0.w;
    h1.h[0] = (_Float16)v1.x; h1.h[1] = (_Float16)v1.y;
    h1.h[2] = (_Float16)v1.z; h1.h[3] = (_Float16)v1.w;
    ((u16x4*)p16)[tid] = h0.u;
    ((u16x4*)p16)[tid + 256] = h1.u;
}

extern "C" void kernel_launch(void* const* d_in, const int* in_sizes, int n_in,
                              void* d_out, int out_size, void* d_ws, size_t ws_size,
                              hipStream_t stream) {
    const float* Q   = (const float*)d_in[0];
    const float* K   = (const float*)d_in[1];
    const float* V   = (const float*)d_in[2];
    const float* W_Q = (const float*)d_in[3];
    const float* W_K = (const float*)d_in[4];
    const float* W_V = (const float*)d_in[5];
    const float* W_O = (const float*)d_in[6];
    const int* masked = (const int*)d_in[7];

    float* out  = (float*)d_out;                    // [4,2048,1024]
    float* attn = out + (size_t)B_ * L_ * D_;       // [4,2048,2048]

    // ws layout (shorts): 8MB weights | qh 16.8 | kh 16.8 | vT 16.8 | attn16 33.6
    short* wq = (short*)d_ws;
    short* wk = wq + (size_t)D_ * D_;
    short* wv = wk + (size_t)D_ * D_;
    short* wo = wv + (size_t)D_ * D_;
    short* qh = wo + (size_t)D_ * D_;               // [8192,1024] f16
    short* kh = qh + (size_t)B_ * L_ * D_;
    short* vT = kh + (size_t)B_ * L_ * D_;          // [4][1024][2048] f16
    short* attn16 = vT + (size_t)B_ * L_ * D_;      // [4][2048][2048] f16
    short* xh = qh;                                 // reuse after scores

    // fp16 Q/K/V copies live in d_out's attn region (dead before scores writes it)
    short* qf = (short*)attn;                       // 3 x 16.8 MB <= 67 MB
    short* kf = qf + (size_t)B_ * L_ * D_;
    short* vf = kf + (size_t)B_ * L_ * D_;

    const long SLD = (long)L_ * D_;
    const long SLL = (long)L_ * L_;

    // 1) weights + inputs fp32 -> fp16
    cvt_w4_k<<<dim3(D_ * D_ / 8 / 256, 4), 256, 0, stream>>>(W_Q, W_K, W_V, W_O, wq);
    cvt_qkv_k<<<dim3(B_ * L_ * D_ / 8 / 256, 3), 256, 0, stream>>>(Q, K, V, qf);

    // 2) fused QKV projections: one dispatch, 1536 blocks, pure-f16 staging
    proj_qkv<<<dim3(D_ / BN, (B_ * L_) / BM, 3), 256, 0, stream>>>(
        qf, kf, vf, wq, wk, wv, qh, kh, vT);

    // 3) scores = q @ k^T / 8 -> fp32 into attn slot (+ faithful mask)
    dim3 gsc(L_ / BN, L_ / BM, B_);
    hgemm<2><<<gsc, 256, 0, stream>>>(qh, kh, attn, L_, L_, D_, SLD, SLD, SLL,
                                      0.125f, 1, masked);

    // 4) softmax rows, in place (fp32) + fp16 copy for PV
    softmax_rows_k<<<dim3(B_ * L_), 256, 0, stream>>>(attn, attn16);

    // 5) x = attn16 @ vT -> f16 x
    dim3 gav(D_ / BN, L_ / BM, B_);
    hgemm<0><<<gav, 256, 0, stream>>>(attn16, vT, xh, L_, D_, L_, SLL, SLD, SLD,
                                      1.f, 0, masked);

    // 6) out = x @ W_O^T -> fp32
    dim3 gproj(D_ / BN, (B_ * L_) / BM, 1);
    hgemm<2><<<gproj, 256, 0, stream>>>(xh, wo, out, B_ * L_, D_, D_, 0, 0, 0,
                                        1.f, 0, masked);
}

// Round 10
// 254.612 us; speedup vs baseline: 1.2911x; 1.0156x over previous
//
#include <hip/hip_runtime.h>
#include <math.h>

// MaskedMultiHeadAttention (B=4, L=2048, D=1024), fp32 in/out, fp16-MFMA internals.
// d_out = [ out : 4*2048*1024 f32 | attn : 4*2048*2048 f32 ]
// ws (92MB): wq wk wv wo (f16) | qh | kh | vT | attn16 (f16); x reuses qh.
// fp16 Q/K/V copies stashed in d_out's attn region (dead before softmax writes it).
// Scores are written UNNORMALIZED as f16 into attn16; softmax reads f16, writes
// the mandatory fp32 attn + normalized f16 in place (saves ~100MB HBM traffic).
// f16 GEMM outputs go through an LDS-bounce epilogue (8 coalesced 16B stores
// per lane instead of 64 scalar 2B stores).

static constexpr int B_ = 4;
static constexpr int L_ = 2048;
static constexpr int D_ = 1024;

#define BM 128
#define BN 128
#define BKK 64   // K-step in elements (fp16)

typedef _Float16 f16x8 __attribute__((ext_vector_type(8)));
typedef float    f32x4 __attribute__((ext_vector_type(4)));
typedef short    s16x8 __attribute__((ext_vector_type(8)));
typedef unsigned short u16x4 __attribute__((ext_vector_type(4)));

typedef __attribute__((address_space(1))) const unsigned int GU32;
typedef __attribute__((address_space(3))) unsigned int LU32;

__device__ __forceinline__ void gload_lds16(const void* g, void* l) {
    __builtin_amdgcn_global_load_lds((GU32*)g, (LU32*)l, 16, 0, 0);
}

__device__ __forceinline__ short f2h_bits(float x) {
    union { _Float16 h; short s; } u;
    u.h = (_Float16)x;
    return u.s;
}

__device__ __forceinline__ s16x8 cvt8h(float4 a, float4 b) {
    union { _Float16 h[8]; s16x8 s; } u;
    u.h[0] = (_Float16)a.x; u.h[1] = (_Float16)a.y;
    u.h[2] = (_Float16)a.z; u.h[3] = (_Float16)a.w;
    u.h[4] = (_Float16)b.x; u.h[5] = (_Float16)b.y;
    u.h[6] = (_Float16)b.z; u.h[7] = (_Float16)b.w;
    return u.s;
}

// One K-step of MFMA work on staged (A,B) LDS tiles.
__device__ __forceinline__ void compute_step(
    const short* __restrict__ As, const short* __restrict__ Bs,
    int wr, int wc, int lr, int lk, f32x4 (&acc)[4][4])
{
#pragma unroll
    for (int kk = 0; kk < 2; ++kk) {
        const int slotk = kk * 4 + lk;
        f16x8 a[4], b[4];
#pragma unroll
        for (int m = 0; m < 4; ++m) {
            const int r = wr * 64 + m * 16 + lr;
            a[m] = *(const f16x8*)&As[r * 64 + ((slotk ^ (r & 7)) << 3)];
        }
#pragma unroll
        for (int n = 0; n < 4; ++n) {
            const int c = wc * 64 + n * 16 + lr;
            b[n] = *(const f16x8*)&Bs[c * 64 + ((slotk ^ (c & 7)) << 3)];
        }
#pragma unroll
        for (int m = 0; m < 4; ++m)
#pragma unroll
            for (int n = 0; n < 4; ++n)
                acc[m][n] = __builtin_amdgcn_mfma_f32_16x16x32_f16(a[m], b[n], acc[m][n], 0, 0, 0);
    }
}

// f16 LDS-bounce epilogue: wave writes its 64x64 f16 tile into its 8KB LDS
// region (XOR-swizzled rows), then stores 8 coalesced 16B chunks per lane.
// APPLY_SM: multiply by scale and apply faithful-buggy tril mask first.
template<int APPLY_SM>
__device__ __forceinline__ void epilogue_f16_bounce(
    short* __restrict__ lw, short* __restrict__ C, long N,
    int bm, int bn, int wr, int wc, int lr, int lk, int lane,
    const f32x4 (&acc)[4][4], float scale, bool msk)
{
#pragma unroll
    for (int m = 0; m < 4; ++m) {
        const int rl0 = m * 16 + lk * 4;
#pragma unroll
        for (int n = 0; n < 4; ++n) {
            const int cl = n * 16 + lr;
            const int slot = cl >> 3, cw = cl & 7;
#pragma unroll
            for (int g = 0; g < 4; ++g) {
                const int rl = rl0 + g;
                float v = acc[m][n][g];
                if constexpr (APPLY_SM) {
                    v *= scale;
                    if (msk && (bn + wc * 64 + cl) <= (bm + wr * 64 + rl)) v = -INFINITY;
                }
                lw[rl * 64 + ((slot ^ (rl & 7)) << 3) + cw] = f2h_bits(v);
            }
        }
    }
    // wave reads only its own region: no barrier needed
    const int l8 = lane & 7, lr8 = lane >> 3;
#pragma unroll
    for (int it = 0; it < 8; ++it) {
        const int rl = it * 8 + lr8;
        const int cl = (l8 ^ (rl & 7)) << 3;   // logical col of physical slot l8
        s16x8 d = *(const s16x8*)&lw[rl * 64 + (l8 << 3)];
        *(s16x8*)&C[(long)(bm + wr * 64 + rl) * N + bn + wc * 64 + cl] = d;
    }
}

// ---------------- fused QKV projection (pure f16 both sides) ----------------
// grid (8, 64, 3): z selects (A16, W, out). M=8192, N=1024, K=1024.
__global__ __launch_bounds__(256) void proj_qkv(
    const short* __restrict__ qf, const short* __restrict__ kf, const short* __restrict__ vf,
    const short* __restrict__ wq, const short* __restrict__ wk, const short* __restrict__ wv,
    short* __restrict__ qh, short* __restrict__ kh, short* __restrict__ vT)
{
    __shared__ short smem[2 * BM * BKK];  // As | Bs, 32 KB
    short* As = smem;
    short* Bs = smem + BM * BKK;

    const int t    = threadIdx.x;
    const int wid  = t >> 6;
    const int lane = t & 63;
    const int bz   = blockIdx.z;

    const short* A16 = (bz == 0) ? qf : (bz == 1) ? kf : vf;
    const short* Bt  = (bz == 0) ? wq : (bz == 1) ? wk : wv;

    const int gx = gridDim.x, gy = gridDim.y;
    const int wg = blockIdx.y * gx + blockIdx.x;
    const int bm = (wg % gy) * BM;   // A-panel pinned to one XCD (gy%8==0)
    const int bn = (wg / gy) * BN;

    const int wr = wid >> 1, wc = wid & 1;
    const int lr = lane & 15, lk = lane >> 4;
    const int srow = t >> 3, sslot = t & 7;
    const int K = D_;

    f32x4 acc[4][4];
#pragma unroll
    for (int m = 0; m < 4; ++m)
#pragma unroll
        for (int n = 0; n < 4; ++n) acc[m][n] = (f32x4)0.f;

    for (int k0 = 0; k0 < K; k0 += BKK) {
        __syncthreads();
#pragma unroll
        for (int i = 0; i < 4; ++i) {
            const int rb = i * 32 + srow;
            const short* g = Bt + (long)(bn + rb) * K + k0 + ((sslot ^ (rb & 7)) << 3);
            gload_lds16(g, &Bs[i * 2048 + wid * 512]);
        }
#pragma unroll
        for (int i = 0; i < 4; ++i) {
            const int ra = i * 32 + srow;
            const short* g = A16 + (long)(bm + ra) * K + k0 + ((sslot ^ (ra & 7)) << 3);
            gload_lds16(g, &As[i * 2048 + wid * 512]);
        }
        __syncthreads();
        compute_step(As, Bs, wr, wc, lr, lk, acc);
    }

    const int N = D_;
    if (bz < 2) {
        __syncthreads();
        short* C = (bz == 0) ? qh : kh;
        epilogue_f16_bounce<0>(smem + wid * 4096, C, N, bm, bn, wr, wc, lr, lk, lane,
                               acc, 1.f, false);
    } else {
#pragma unroll
        for (int m = 0; m < 4; ++m) {
            const int rg = bm + wr * 64 + m * 16 + lk * 4;
            const long rb = (long)(rg >> 11) * ((long)N * L_) + (rg & (L_ - 1));
#pragma unroll
            for (int n = 0; n < 4; ++n) {
                const int c = bn + wc * 64 + n * 16 + lr;
                u16x4 v;
#pragma unroll
                for (int g = 0; g < 4; ++g) v[g] = (unsigned short)f2h_bits(acc[m][n][g]);
                *(u16x4*)&vT[rb + (long)c * L_] = v;
            }
        }
    }
}

// ---------------- generic f16 GEMM ----------------
// C[M,N](+batch) = scale * A[M,K] @ Bt[N,K]^T; A,B f16 via global_load_lds.
// OMODE: 0 = f16 [M,N]; 2 = f32 (out-proj); 3 = f16 with scale + tril mask (scores).
template<int OMODE>
__global__ __launch_bounds__(256) void hgemm(
    const short* __restrict__ A16p, const short* __restrict__ Btp, void* __restrict__ Cp_,
    int M, int N, int K, long sA, long sB, long sC,
    float scale, int useMask, const int* __restrict__ mflag)
{
    __shared__ short smem[2 * BM * BKK];
    short* As = smem;
    short* Bs = smem + BM * BKK;

    const int t    = threadIdx.x;
    const int wid  = t >> 6;
    const int lane = t & 63;
    const int bz   = blockIdx.z;

    const int gx = gridDim.x, gy = gridDim.y;
    const int wg = blockIdx.y * gx + blockIdx.x;
    const int bm = (wg % gy) * BM;
    const int bn = (wg / gy) * BN;

    const short* Bt  = Btp + (long)bz * sB;
    const short* A16 = A16p + (long)bz * sA;

    const int wr = wid >> 1, wc = wid & 1;
    const int lr = lane & 15, lk = lane >> 4;
    const int srow = t >> 3, sslot = t & 7;

    f32x4 acc[4][4];
#pragma unroll
    for (int m = 0; m < 4; ++m)
#pragma unroll
        for (int n = 0; n < 4; ++n) acc[m][n] = (f32x4)0.f;

    for (int k0 = 0; k0 < K; k0 += BKK) {
        __syncthreads();
#pragma unroll
        for (int i = 0; i < 4; ++i) {
            const int rb = i * 32 + srow;
            const short* g = Bt + (long)(bn + rb) * K + k0 + ((sslot ^ (rb & 7)) << 3);
            gload_lds16(g, &Bs[i * 2048 + wid * 512]);
        }
#pragma unroll
        for (int i = 0; i < 4; ++i) {
            const int ra = i * 32 + srow;
            const short* g = A16 + (long)(bm + ra) * K + k0 + ((sslot ^ (ra & 7)) << 3);
            gload_lds16(g, &As[i * 2048 + wid * 512]);
        }
        __syncthreads();
        compute_step(As, Bs, wr, wc, lr, lk, acc);
    }

    if constexpr (OMODE == 2) {
        float* C = (float*)Cp_ + (long)bz * sC;
#pragma unroll
        for (int m = 0; m < 4; ++m) {
            const int r0 = bm + wr * 64 + m * 16 + lk * 4;
#pragma unroll
            for (int n = 0; n < 4; ++n) {
                const int c = bn + wc * 64 + n * 16 + lr;
#pragma unroll
                for (int g = 0; g < 4; ++g)
                    C[(long)(r0 + g) * N + c] = acc[m][n][g] * scale;
            }
        }
    } else {
        __syncthreads();
        short* C = (short*)Cp_ + (long)bz * sC;
        const bool msk = (OMODE == 3) && useMask && (mflag[0] != 0);
        epilogue_f16_bounce<(OMODE == 3) ? 1 : 0>(
            smem + wid * 4096, C, N, bm, bn, wr, wc, lr, lk, lane, acc, scale, msk);
    }
}

// fp32 -> fp16 for the 4 weight matrices in one dispatch (grid.y selects W)
__global__ __launch_bounds__(256) void cvt_w4_k(
    const float* __restrict__ W_Q, const float* __restrict__ W_K,
    const float* __restrict__ W_V, const float* __restrict__ W_O,
    short* __restrict__ dst)
{
    const int w = blockIdx.y;
    const float* src = (w == 0) ? W_Q : (w == 1) ? W_K : (w == 2) ? W_V : W_O;
    short* out = dst + (size_t)w * D_ * D_;
    const int i = blockIdx.x * 256 + threadIdx.x;
    float4 a = ((const float4*)src)[2 * i];
    float4 b = ((const float4*)src)[2 * i + 1];
    *(s16x8*)&out[i * 8] = cvt8h(a, b);
}

// fp32 -> fp16 for Q,K,V in one dispatch (grid.y selects tensor)
__global__ __launch_bounds__(256) void cvt_qkv_k(
    const float* __restrict__ Q, const float* __restrict__ K,
    const float* __restrict__ V, short* __restrict__ dst)
{
    const int w = blockIdx.y;
    const float* src = (w == 0) ? Q : (w == 1) ? K : V;
    short* out = dst + (size_t)w * B_ * L_ * D_;
    const int i = blockIdx.x * 256 + threadIdx.x;
    float4 a = ((const float4*)src)[2 * i];
    float4 b = ((const float4*)src)[2 * i + 1];
    *(s16x8*)&out[i * 8] = cvt8h(a, b);
}

// row softmax over f16 unnormalized scores (rows of 2048):
// writes fp32 normalized attn (d_out) + f16 normalized copy in place.
__global__ __launch_bounds__(256) void softmax_rows_k(
    short* __restrict__ S16, float* __restrict__ Sout)
{
    const long row = blockIdx.x;
    short* p16 = S16 + row * (long)L_;
    float* pf  = Sout + row * (long)L_;
    const int tid = threadIdx.x;

    union { s16x8 v; _Float16 h[8]; } u;
    u.v = ((const s16x8*)p16)[tid];
    float f[8];
#pragma unroll
    for (int j = 0; j < 8; ++j) f[j] = (float)u.h[j];

    float m = f[0];
#pragma unroll
    for (int j = 1; j < 8; ++j) m = fmaxf(m, f[j]);
#pragma unroll
    for (int o = 32; o > 0; o >>= 1) m = fmaxf(m, __shfl_xor(m, o, 64));

    __shared__ float wmax[4], wsum[4];
    if ((tid & 63) == 0) wmax[tid >> 6] = m;
    __syncthreads();
    m = fmaxf(fmaxf(wmax[0], wmax[1]), fmaxf(wmax[2], wmax[3]));

    float s = 0.f;
#pragma unroll
    for (int j = 0; j < 8; ++j) { f[j] = expf(f[j] - m); s += f[j]; }
#pragma unroll
    for (int o = 32; o > 0; o >>= 1) s += __shfl_xor(s, o, 64);
    if ((tid & 63) == 0) wsum[tid >> 6] = s;
    __syncthreads();
    s = wsum[0] + wsum[1] + wsum[2] + wsum[3];

    const float inv = 1.f / s;
#pragma unroll
    for (int j = 0; j < 8; ++j) f[j] = f[j] * inv;

    float4 a, b;
    a.x = f[0]; a.y = f[1]; a.z = f[2]; a.w = f[3];
    b.x = f[4]; b.y = f[5]; b.z = f[6]; b.w = f[7];
    ((float4*)pf)[2 * tid]     = a;
    ((float4*)pf)[2 * tid + 1] = b;
    ((s16x8*)p16)[tid] = cvt8h(a, b);
}

extern "C" void kernel_launch(void* const* d_in, const int* in_sizes, int n_in,
                              void* d_out, int out_size, void* d_ws, size_t ws_size,
                              hipStream_t stream) {
    const float* Q   = (const float*)d_in[0];
    const float* K   = (const float*)d_in[1];
    const float* V   = (const float*)d_in[2];
    const float* W_Q = (const float*)d_in[3];
    const float* W_K = (const float*)d_in[4];
    const float* W_V = (const float*)d_in[5];
    const float* W_O = (const float*)d_in[6];
    const int* masked = (const int*)d_in[7];

    float* out  = (float*)d_out;                    // [4,2048,1024]
    float* attn = out + (size_t)B_ * L_ * D_;       // [4,2048,2048]

    // ws layout (shorts): 8MB weights | qh 16.8 | kh 16.8 | vT 16.8 | attn16 33.6
    short* wq = (short*)d_ws;
    short* wk = wq + (size_t)D_ * D_;
    short* wv = wk + (size_t)D_ * D_;
    short* wo = wv + (size_t)D_ * D_;
    short* qh = wo + (size_t)D_ * D_;               // [8192,1024] f16
    short* kh = qh + (size_t)B_ * L_ * D_;
    short* vT = kh + (size_t)B_ * L_ * D_;          // [4][1024][2048] f16
    short* attn16 = vT + (size_t)B_ * L_ * D_;      // [4][2048][2048] f16
    short* xh = qh;                                 // reuse after scores

    // fp16 Q/K/V copies live in d_out's attn region (dead before softmax writes it)
    short* qf = (short*)attn;                       // 3 x 16.8 MB <= 67 MB
    short* kf = qf + (size_t)B_ * L_ * D_;
    short* vf = kf + (size_t)B_ * L_ * D_;

    const long SLD = (long)L_ * D_;
    const long SLL = (long)L_ * L_;

    // 1) weights + inputs fp32 -> fp16
    cvt_w4_k<<<dim3(D_ * D_ / 8 / 256, 4), 256, 0, stream>>>(W_Q, W_K, W_V, W_O, wq);
    cvt_qkv_k<<<dim3(B_ * L_ * D_ / 8 / 256, 3), 256, 0, stream>>>(Q, K, V, qf);

    // 2) fused QKV projections: one dispatch, 1536 blocks, pure-f16 staging
    proj_qkv<<<dim3(D_ / BN, (B_ * L_) / BM, 3), 256, 0, stream>>>(
        qf, kf, vf, wq, wk, wv, qh, kh, vT);

    // 3) scores = q @ k^T / 8 -> f16 UNNORMALIZED into attn16 (+ faithful mask)
    dim3 gsc(L_ / BN, L_ / BM, B_);
    hgemm<3><<<gsc, 256, 0, stream>>>(qh, kh, attn16, L_, L_, D_, SLD, SLD, SLL,
                                      0.125f, 1, masked);

    // 4) softmax rows: read f16 scores, write fp32 attn + normalized f16 in place
    softmax_rows_k<<<dim3(B_ * L_), 256, 0, stream>>>(attn16, attn);

    // 5) x = attn16 @ vT -> f16 x
    dim3 gav(D_ / BN, L_ / BM, B_);
    hgemm<0><<<gav, 256, 0, stream>>>(attn16, vT, xh, L_, D_, L_, SLL, SLD, SLD,
                                      1.f, 0, masked);

    // 6) out = x @ W_O^T -> fp32
    dim3 gproj(D_ / BN, (B_ * L_) / BM, 1);
    hgemm<2><<<gproj, 256, 0, stream>>>(xh, wo, out, B_ * L_, D_, D_, 0, 0, 0,
                                        1.f, 0, masked);
}